// Round 8
// baseline (1392.299 us; speedup 1.0000x reference)
//
#include <hip/hip_runtime.h>
#include <cmath>

// b=4, c=512, h=w=64 -> n=4096, groups=32 (16 ch/group)
#define NB 4
#define NC 512
#define NN 4096
#define ATTN_SCALE 0.04419417382415922f  // 512^-0.5

typedef __bf16 bf16x8 __attribute__((ext_vector_type(8)));
typedef float floatx4 __attribute__((ext_vector_type(4)));

__device__ __forceinline__ unsigned short f2bf(float f) {
    union { float f; unsigned int u; } v; v.f = f;
    return (unsigned short)((v.u + 0x7fffu + ((v.u >> 16) & 1u)) >> 16);
}
__device__ __forceinline__ unsigned short f2bf_trunc(float f) {
    union { float f; unsigned int u; } v; v.f = f;
    return (unsigned short)(v.u >> 16);
}

// ---------------------------------------------------------------------------
// Kernel 1a: GroupNorm partial sums. 1024 blocks = (b,g) x 8 slices.
// ---------------------------------------------------------------------------
__global__ __launch_bounds__(256) void gn_partial_kernel(
    const float* __restrict__ x, float* __restrict__ part)
{
    int blk = blockIdx.x;
    int bg = blk >> 3, sub = blk & 7;
    const float4* xv = (const float4*)(x + (size_t)bg * 16 * NN + (size_t)sub * 8192);
    float s1 = 0.f, s2 = 0.f;
#pragma unroll
    for (int i = 0; i < 8; ++i) {
        float4 v = xv[threadIdx.x + i * 256];
        s1 += v.x + v.y + v.z + v.w;
        s2 += v.x * v.x + v.y * v.y + v.z * v.z + v.w * v.w;
    }
#pragma unroll
    for (int off = 32; off; off >>= 1) {
        s1 += __shfl_xor(s1, off, 64);
        s2 += __shfl_xor(s2, off, 64);
    }
    __shared__ float r1[4], r2[4];
    int lane = threadIdx.x & 63, w = threadIdx.x >> 6;
    if (lane == 0) { r1[w] = s1; r2[w] = s2; }
    __syncthreads();
    if (threadIdx.x == 0) {
        part[blk * 2]     = r1[0] + r1[1] + r1[2] + r1[3];
        part[blk * 2 + 1] = r2[0] + r2[1] + r2[2] + r2[3];
    }
}

// Kernel 1b: finalize -> per-channel scale/shift
__global__ __launch_bounds__(128) void gn_final_kernel(
    const float* __restrict__ part, const float* __restrict__ gw,
    const float* __restrict__ gb, float* __restrict__ ss)
{
    int tg = threadIdx.x;            // 0..127 = b*32+g
    int b = tg >> 5, g = tg & 31;
    float s1 = 0.f, s2 = 0.f;
#pragma unroll
    for (int s = 0; s < 8; ++s) {
        s1 += part[(tg * 8 + s) * 2];
        s2 += part[(tg * 8 + s) * 2 + 1];
    }
    float mean = s1 * (1.0f / 65536.0f);
    float var  = s2 * (1.0f / 65536.0f) - mean * mean;
    float rstd = rsqrtf(var + 1e-5f);
#pragma unroll
    for (int i = 0; i < 16; ++i) {
        int c = g * 16 + i;
        float sc = rstd * gw[c];
        ss[b * NC + c] = sc;
        ss[2048 + b * NC + c] = gb[c] - mean * sc;
    }
}

// ---------------------------------------------------------------------------
// Kernel 2: convert weights fp32 -> bf16
// ---------------------------------------------------------------------------
__global__ __launch_bounds__(256) void wconv_kernel(
    const float* __restrict__ qkv_w, const float* __restrict__ out_w,
    unsigned short* __restrict__ wq, unsigned short* __restrict__ wo)
{
    int i = blockIdx.x * 256 + threadIdx.x;
    const int NQ = 1536 * 512;
    if (i < NQ) wq[i] = f2bf(qkv_w[i]);
    else        wo[i - NQ] = f2bf(out_w[i - NQ]);
}

// ---------------------------------------------------------------------------
// Kernel 3: normalize + transpose: x (b,c,n) fp32 -> h_t (b,n,c) bf16
// ---------------------------------------------------------------------------
__global__ __launch_bounds__(256) void htnorm_kernel(
    const float* __restrict__ x, const float* __restrict__ ss,
    unsigned short* __restrict__ ht)
{
    int b = blockIdx.z;
    int c0 = blockIdx.y * 32, n0 = blockIdx.x * 32;
    __shared__ float T[32][33];
    int tx = threadIdx.x & 31, ty = threadIdx.x >> 5;   // ty 0..7
    const float* xb = x + ((size_t)b * NC + c0) * NN;
    const float* sc = ss + b * NC + c0;
    const float* sh = ss + 2048 + b * NC + c0;
#pragma unroll
    for (int i = 0; i < 4; ++i) {
        int c = ty + i * 8;
        T[c][tx] = xb[(size_t)c * NN + n0 + tx] * sc[c] + sh[c];
    }
    __syncthreads();
    unsigned short* hb = ht + ((size_t)b * NN + n0) * NC + c0;
#pragma unroll
    for (int i = 0; i < 4; ++i) {
        int n = ty + i * 8;
        hb[(size_t)n * NC + tx] = f2bf(T[tx][n]);
    }
}

// ---------------------------------------------------------------------------
// Barrier-free direct MFMA GEMM. C[m,n] = sum_k A[m,k]*B[n,k] (both K-major).
// Block = 4 waves; each wave owns a 16(m) x 128(n) C-tile; fragments loaded
// directly global->VGPR (16B/lane, 16 cache lines per load = fully coalesced).
// No LDS, no __syncthreads -> compiler pipelines with fine-grained vmcnt(N).
// B regs double-buffered; A ring depth 4 (covers HBM/L3 latency on SP).
// MODE 0: qkv q/k  M=4096 N=1024 K=512  A=ht(+z) B=wqk   -> qt(*scale)/kt +bias
// MODE 1: qkv v    M=512  N=4096 K=512  A=wv     B=ht(+z)-> vt (c,p) +bias
// MODE 2: QK^T     M=4096 N=4096 K=512  A=qt(+z) B=kt(+z)-> SP=exp(s) bf16 + L
// MODE 3: PV       M=4096 N=512  K=4096 A=SP(+z) B=vt(+z)-> Ob (p,c), /L[p]
// MODE 4: out proj M=512  N=4096 K=512  A=wo     B=Ob(+z)-> out fp32 +bias+res
// ---------------------------------------------------------------------------
template<int MODE>
__global__ __launch_bounds__(256) void dgemm(
    const unsigned short* __restrict__ Abase,
    const unsigned short* __restrict__ Bbase,
    const float* __restrict__ e0, const float* __restrict__ e1,
    float* __restrict__ outf,
    unsigned short* __restrict__ ob0, unsigned short* __restrict__ ob1)
{
    constexpr int K = (MODE == 3) ? 4096 : 512;
    constexpr int ITER = K / 32;
    const int z = blockIdx.z;
    const size_t bnc = (size_t)NN * NC;
    const size_t bss = (size_t)NN * NN;

    const unsigned short* A;
    const unsigned short* B;
    if constexpr (MODE == 0)      { A = Abase + (size_t)z * bnc; B = Bbase; }
    else if constexpr (MODE == 1) { A = Abase; B = Bbase + (size_t)z * bnc; }
    else if constexpr (MODE == 2) { A = Abase + (size_t)z * bnc; B = Bbase + (size_t)z * bnc; }
    else if constexpr (MODE == 3) { A = Abase + (size_t)z * bss; B = Bbase + (size_t)z * bnc; }
    else                          { A = Abase; B = Bbase + (size_t)z * bnc; }

    const int t = threadIdx.x;
    const int lane = t & 63;
    const int w = t >> 6;
    const int r = lane & 15;          // fragment row/col within 16
    const int q = lane >> 4;          // k-group
    const int mw = blockIdx.y * 64 + w * 16;   // wave's 16-row strip
    const int n0 = blockIdx.x * 128;

    const unsigned short* Ap = A + (size_t)(mw + r) * K + q * 8;
    const unsigned short* Bp = B + (size_t)(n0 + r) * K + q * 8;

    bf16x8 a[4], b[2][8];
    floatx4 acc[8] = {};

    // prologue: A 3 deep, B 1 deep
    a[0] = *(const bf16x8*)(Ap);
    a[1] = *(const bf16x8*)(Ap + 32);
    a[2] = *(const bf16x8*)(Ap + 64);
#pragma unroll
    for (int j = 0; j < 8; ++j)
        b[0][j] = *(const bf16x8*)(Bp + (size_t)j * 16 * K);

#pragma unroll
    for (int kt = 0; kt < ITER; ++kt) {
        const int cur = kt & 1;
        if (kt + 1 < ITER) {
            const unsigned short* Bn = Bp + (kt + 1) * 32;
#pragma unroll
            for (int j = 0; j < 8; ++j)
                b[cur ^ 1][j] = *(const bf16x8*)(Bn + (size_t)j * 16 * K);
        }
        if (kt + 3 < ITER)
            a[(kt + 3) & 3] = *(const bf16x8*)(Ap + (kt + 3) * 32);
#pragma unroll
        for (int j = 0; j < 8; ++j)
            acc[j] = __builtin_amdgcn_mfma_f32_16x16x32_bf16(
                a[kt & 3], b[cur][j], acc[j], 0, 0, 0);
    }

    // Epilogue. C/D: col = r, row = q*4 + reg (within wave's 16-row strip)
    if constexpr (MODE == 2) {
        float rs[4] = {};
#pragma unroll
        for (int j = 0; j < 8; ++j) {
            int n = n0 + j * 16 + r;
#pragma unroll
            for (int reg = 0; reg < 4; ++reg) {
                int m = mw + q * 4 + reg;
                float e = __expf(acc[j][reg]);
                ob0[(size_t)z * bss + (size_t)m * NN + n] = f2bf_trunc(e);
                rs[reg] += e;
            }
        }
#pragma unroll
        for (int reg = 0; reg < 4; ++reg) {
            float v = rs[reg];
            v += __shfl_xor(v, 1, 16);
            v += __shfl_xor(v, 2, 16);
            v += __shfl_xor(v, 4, 16);
            v += __shfl_xor(v, 8, 16);
            if (r == 0)
                atomicAdd(&outf[z * NN + mw + q * 4 + reg], v);
        }
        return;
    }

    if constexpr (MODE == 3) {
        float linv[4];
#pragma unroll
        for (int reg = 0; reg < 4; ++reg)
            linv[reg] = 1.0f / e0[z * NN + mw + q * 4 + reg];
#pragma unroll
        for (int j = 0; j < 8; ++j) {
            int n = n0 + j * 16 + r;
#pragma unroll
            for (int reg = 0; reg < 4; ++reg) {
                int m = mw + q * 4 + reg;
                ob0[(size_t)z * bnc + (size_t)m * NC + n] = f2bf(acc[j][reg] * linv[reg]);
            }
        }
        return;
    }

#pragma unroll
    for (int j = 0; j < 8; ++j) {
        int n = n0 + j * 16 + r;
#pragma unroll
        for (int reg = 0; reg < 4; ++reg) {
            int m = mw + q * 4 + reg;
            float val = acc[j][reg];
            if constexpr (MODE == 0) {
                val += e0[n];   // qkv bias, o = n in [0,1024)
                if (n < 512) ob0[((size_t)z * NN + m) * NC + n] = f2bf(val * ATTN_SCALE);
                else         ob1[((size_t)z * NN + m) * NC + (n - 512)] = f2bf(val);
            } else if constexpr (MODE == 1) {
                val += e0[1024 + m];   // v bias, channel = m
                ob0[((size_t)z * NC + m) * NN + n] = f2bf(val);
            } else {   // MODE 4
                size_t idx = ((size_t)z * NC + m) * NN + n;
                outf[idx] = val + e0[m] + e1[idx];
            }
        }
    }
}

// ---------------------------------------------------------------------------
extern "C" void kernel_launch(void* const* d_in, const int* in_sizes, int n_in,
                              void* d_out, int out_size, void* d_ws, size_t ws_size,
                              hipStream_t stream)
{
    const float* x     = (const float*)d_in[0];
    const float* gn_w  = (const float*)d_in[1];
    const float* gn_b  = (const float*)d_in[2];
    const float* qkv_w = (const float*)d_in[3];
    const float* qkv_b = (const float*)d_in[4];
    const float* out_w = (const float*)d_in[5];
    const float* out_b = (const float*)d_in[6];
    float* out = (float*)d_out;

    const size_t bnc = (size_t)NN * NC;          // 2,097,152 per batch
    char* w = (char*)d_ws;
    float* ss   = (float*)w;                 w += 16384;
    float* part = (float*)w;                 w += 8192;
    float* Lsum = (float*)w;                 w += (size_t)NB * NN * 4;  // row sums
    unsigned short* wq = (unsigned short*)w; w += (size_t)1536 * 512 * 2;
    unsigned short* wo = (unsigned short*)w; w += (size_t)512 * 512 * 2;
    unsigned short* qt = (unsigned short*)w; w += NB * bnc * 2;   // (b,n,c) pre-scaled
    unsigned short* kt = (unsigned short*)w; w += NB * bnc * 2;   // (b,n,c)
    unsigned short* vt = (unsigned short*)w; w += NB * bnc * 2;   // (b,c,n)
    unsigned short* SP = (unsigned short*)w; w += (size_t)NB * NN * NN * 2; // 128 MB
    // Aliases (lifetime-disjoint):
    unsigned short* ht = SP;   // ht (b,n,c) dead before MODE 2 writes SP
    unsigned short* Ob = qt;   // Ob (b,n,c) written after qt last read (MODE 2)

    hipMemsetAsync(Lsum, 0, (size_t)NB * NN * sizeof(float), stream);

    gn_partial_kernel<<<1024, 256, 0, stream>>>(x, part);
    gn_final_kernel<<<1, 128, 0, stream>>>(part, gn_w, gn_b, ss);
    wconv_kernel<<<(1536 * 512 + 512 * 512) / 256, 256, 0, stream>>>(qkv_w, out_w, wq, wo);
    htnorm_kernel<<<dim3(NN / 32, NC / 32, NB), 256, 0, stream>>>(x, ss, ht);

    // q/k: C[p,o] = ht · wqk^T   (q pre-scaled by ATTN_SCALE)
    dgemm<0><<<dim3(1024 / 128, NN / 64, NB), 256, 0, stream>>>(
        ht, wq, qkv_b, nullptr, nullptr, qt, kt);
    // v: C[c,p] = wv · ht^T
    dgemm<1><<<dim3(NN / 128, 512 / 64, NB), 256, 0, stream>>>(
        wq + (size_t)1024 * 512, ht, qkv_b, nullptr, nullptr, vt, nullptr);

    // QK^T + exp + row-sum accumulation, all batches
    dgemm<2><<<dim3(NN / 128, NN / 64, NB), 256, 0, stream>>>(
        qt, kt, nullptr, nullptr, Lsum, SP, nullptr);
    // PV + normalize, all batches
    dgemm<3><<<dim3(512 / 128, NN / 64, NB), 256, 0, stream>>>(
        SP, vt, Lsum, nullptr, nullptr, Ob, nullptr);

    // out projection + bias + residual
    dgemm<4><<<dim3(NN / 128, 512 / 64, NB), 256, 0, stream>>>(
        wo, Ob, out_b, x, out, nullptr, nullptr);
}

// Round 9
// 418.352 us; speedup vs baseline: 3.3281x; 3.3281x over previous
//
#include <hip/hip_runtime.h>
#include <cmath>

// b=4, c=512, h=w=64 -> n=4096, groups=32 (16 ch/group)
#define NB 4
#define NC 512
#define NN 4096
#define ATTN_SCALE 0.04419417382415922f  // 512^-0.5

typedef __bf16 bf16x8 __attribute__((ext_vector_type(8)));
typedef float floatx4 __attribute__((ext_vector_type(4)));

__device__ __forceinline__ unsigned short f2bf(float f) {
    union { float f; unsigned int u; } v; v.f = f;
    return (unsigned short)((v.u + 0x7fffu + ((v.u >> 16) & 1u)) >> 16);
}
__device__ __forceinline__ unsigned short f2bf_trunc(float f) {
    union { float f; unsigned int u; } v; v.f = f;
    return (unsigned short)(v.u >> 16);
}

__device__ __forceinline__ void gload_lds16(const unsigned short* gp, unsigned short* lp) {
    __builtin_amdgcn_global_load_lds(
        (const __attribute__((address_space(1))) void*)gp,
        (__attribute__((address_space(3))) void*)lp, 16, 0, 0);
}

// ---------------------------------------------------------------------------
// Kernel 1a: GroupNorm partial sums. 1024 blocks = (b,g) x 8 slices.
// ---------------------------------------------------------------------------
__global__ __launch_bounds__(256) void gn_partial_kernel(
    const float* __restrict__ x, float* __restrict__ part)
{
    int blk = blockIdx.x;
    int bg = blk >> 3, sub = blk & 7;
    const float4* xv = (const float4*)(x + (size_t)bg * 16 * NN + (size_t)sub * 8192);
    float s1 = 0.f, s2 = 0.f;
#pragma unroll
    for (int i = 0; i < 8; ++i) {
        float4 v = xv[threadIdx.x + i * 256];
        s1 += v.x + v.y + v.z + v.w;
        s2 += v.x * v.x + v.y * v.y + v.z * v.z + v.w * v.w;
    }
#pragma unroll
    for (int off = 32; off; off >>= 1) {
        s1 += __shfl_xor(s1, off, 64);
        s2 += __shfl_xor(s2, off, 64);
    }
    __shared__ float r1[4], r2[4];
    int lane = threadIdx.x & 63, w = threadIdx.x >> 6;
    if (lane == 0) { r1[w] = s1; r2[w] = s2; }
    __syncthreads();
    if (threadIdx.x == 0) {
        part[blk * 2]     = r1[0] + r1[1] + r1[2] + r1[3];
        part[blk * 2 + 1] = r2[0] + r2[1] + r2[2] + r2[3];
    }
}

// Kernel 1b: finalize -> per-channel scale/shift
__global__ __launch_bounds__(128) void gn_final_kernel(
    const float* __restrict__ part, const float* __restrict__ gw,
    const float* __restrict__ gb, float* __restrict__ ss)
{
    int tg = threadIdx.x;            // 0..127 = b*32+g
    int b = tg >> 5, g = tg & 31;
    float s1 = 0.f, s2 = 0.f;
#pragma unroll
    for (int s = 0; s < 8; ++s) {
        s1 += part[(tg * 8 + s) * 2];
        s2 += part[(tg * 8 + s) * 2 + 1];
    }
    float mean = s1 * (1.0f / 65536.0f);
    float var  = s2 * (1.0f / 65536.0f) - mean * mean;
    float rstd = rsqrtf(var + 1e-5f);
#pragma unroll
    for (int i = 0; i < 16; ++i) {
        int c = g * 16 + i;
        float sc = rstd * gw[c];
        ss[b * NC + c] = sc;
        ss[2048 + b * NC + c] = gb[c] - mean * sc;
    }
}

// ---------------------------------------------------------------------------
// Kernel 2: convert weights fp32 -> bf16
// ---------------------------------------------------------------------------
__global__ __launch_bounds__(256) void wconv_kernel(
    const float* __restrict__ qkv_w, const float* __restrict__ out_w,
    unsigned short* __restrict__ wq, unsigned short* __restrict__ wo)
{
    int i = blockIdx.x * 256 + threadIdx.x;
    const int NQ = 1536 * 512;
    if (i < NQ) wq[i] = f2bf(qkv_w[i]);
    else        wo[i - NQ] = f2bf(out_w[i - NQ]);
}

// ---------------------------------------------------------------------------
// Kernel 3: normalize + transpose: x (b,c,n) fp32 -> h_t (b,n,c) bf16
// ---------------------------------------------------------------------------
__global__ __launch_bounds__(256) void htnorm_kernel(
    const float* __restrict__ x, const float* __restrict__ ss,
    unsigned short* __restrict__ ht)
{
    int b = blockIdx.z;
    int c0 = blockIdx.y * 32, n0 = blockIdx.x * 32;
    __shared__ float T[32][33];
    int tx = threadIdx.x & 31, ty = threadIdx.x >> 5;   // ty 0..7
    const float* xb = x + ((size_t)b * NC + c0) * NN;
    const float* sc = ss + b * NC + c0;
    const float* sh = ss + 2048 + b * NC + c0;
#pragma unroll
    for (int i = 0; i < 4; ++i) {
        int c = ty + i * 8;
        T[c][tx] = xb[(size_t)c * NN + n0 + tx] * sc[c] + sh[c];
    }
    __syncthreads();
    unsigned short* hb = ht + ((size_t)b * NN + n0) * NC + c0;
#pragma unroll
    for (int i = 0; i < 4; ++i) {
        int n = ty + i * 8;
        hb[(size_t)n * NC + tx] = f2bf(T[tx][n]);
    }
}

// ---------------------------------------------------------------------------
// MFMA NT GEMM (projection modes), BMxBN tile, BK=32, K=512.
// MODE 0: qkv q/k   M=4096 N=1024  A=ht(+z) B=wqk    -> qt(*scale)/kt +bias
// MODE 1: qkv v     M=512  N=4096  A=wv     B=ht(+z) -> vt (c,p) bf16 +bias
// MODE 4: out proj  M=512  N=4096  A=wo     B=Ob(+z) -> out fp32 +bias+res
// ---------------------------------------------------------------------------
template<int MODE, int BM, int BN>
__global__ __launch_bounds__(256, 3) void mfma_gemm(
    const unsigned short* __restrict__ Abase,
    const unsigned short* __restrict__ Bbase,
    const float* __restrict__ e0, const float* __restrict__ e1,
    float* __restrict__ outf,
    unsigned short* __restrict__ ob0, unsigned short* __restrict__ ob1)
{
    constexpr int K = 512;
    constexpr int FI = BM / 32;
    constexpr int FJ = BN / 32;
    const int z = blockIdx.z;
    const size_t bnc = (size_t)NN * NC;

    const unsigned short* A;
    const unsigned short* B;
    if constexpr (MODE == 0)      { A = Abase + (size_t)z * bnc; B = Bbase; }
    else if constexpr (MODE == 1) { A = Abase; B = Bbase + (size_t)z * bnc; }
    else                          { A = Abase; B = Bbase + (size_t)z * bnc; }

    const int m0 = blockIdx.y * BM;
    const int n0 = blockIdx.x * BN;

    __shared__ __attribute__((aligned(16))) unsigned short As[BM * 32];
    __shared__ __attribute__((aligned(16))) unsigned short Bs[BN * 32];

    const int t = threadIdx.x;
    const int lane = t & 63;
    const int w = t >> 6;
    const int wr = w >> 1, wc = w & 1;

    const int sr = w * 16 + (lane >> 2);
    const int sc8 = (lane & 3) * 8;
    const int lds_elem = w * 512;

    floatx4 acc[FI][FJ] = {};

    for (int k0 = 0; k0 < K; k0 += 32) {
#pragma unroll
        for (int s = 0; s < BM / 64; ++s)
            gload_lds16(A + (size_t)(m0 + s * 64 + sr) * K + k0 + sc8,
                        As + s * 2048 + lds_elem);
#pragma unroll
        for (int s = 0; s < BN / 64; ++s)
            gload_lds16(B + (size_t)(n0 + s * 64 + sr) * K + k0 + sc8,
                        Bs + s * 2048 + lds_elem);
        __syncthreads();

        bf16x8 af[FI], bfr[FJ];
        const unsigned short* Ab = As + ((wr * (BM / 2) + (lane & 15)) * 32) + (lane >> 4) * 8;
        const unsigned short* Bb = Bs + ((wc * (BN / 2) + (lane & 15)) * 32) + (lane >> 4) * 8;
#pragma unroll
        for (int i = 0; i < FI; ++i) af[i]  = *(const bf16x8*)(Ab + i * 16 * 32);
#pragma unroll
        for (int j = 0; j < FJ; ++j) bfr[j] = *(const bf16x8*)(Bb + j * 16 * 32);
#pragma unroll
        for (int i = 0; i < FI; ++i)
#pragma unroll
            for (int j = 0; j < FJ; ++j)
                acc[i][j] = __builtin_amdgcn_mfma_f32_16x16x32_bf16(
                    af[i], bfr[j], acc[i][j], 0, 0, 0);
        __syncthreads();
    }

    const int fr = lane >> 4;
    const int fc = lane & 15;
#pragma unroll
    for (int i = 0; i < FI; ++i) {
#pragma unroll
        for (int j = 0; j < FJ; ++j) {
            int n = n0 + wc * (BN / 2) + j * 16 + fc;
            int mbase = m0 + wr * (BM / 2) + i * 16 + fr * 4;
#pragma unroll
            for (int r = 0; r < 4; ++r) {
                int m = mbase + r;
                float val = acc[i][j][r];
                if constexpr (MODE == 0) {
                    val += e0[n];
                    if (n < 512) ob0[((size_t)z * NN + m) * NC + n] = f2bf(val * ATTN_SCALE);
                    else         ob1[((size_t)z * NN + m) * NC + (n - 512)] = f2bf(val);
                } else if constexpr (MODE == 1) {
                    val += e0[1024 + m];
                    ob0[((size_t)z * NC + m) * NN + n] = f2bf(val);
                } else {   // MODE 4
                    size_t idx = ((size_t)z * NC + m) * NN + n;
                    outf[idx] = val + e0[m] + e1[idx];
                }
            }
        }
    }
}

// ---------------------------------------------------------------------------
// Attention GEMMs with supertile-swizzled 1D grid (L2/XCD locality).
// Tile grid TX x TY, supertiles SW x SH; 32-consecutive-block windows touch
// SW B-panels + SH A-panels -> fits per-XCD L2.
// MODE 2: QK^T  M=4096 N=4096 K=512   A=qt(+z) B=kt(+z) -> SP=exp(s) bf16 + L
// MODE 3: PV    M=4096 N=512  K=4096  A=SP(+z) B=vt(+z) -> Ob (p,c), /L[p]
// ---------------------------------------------------------------------------
template<int MODE, int BM, int BN, int TX, int SW, int SH>
__global__ __launch_bounds__(256, 4) void attn_gemm(
    const unsigned short* __restrict__ Abase,
    const unsigned short* __restrict__ Bbase,
    float* __restrict__ L,
    unsigned short* __restrict__ ob0)
{
    constexpr int K = (MODE == 3) ? 4096 : 512;
    constexpr int FI = BM / 32;
    constexpr int FJ = BN / 32;
    const int z = blockIdx.z;
    const size_t bnc = (size_t)NN * NC;
    const size_t bss = (size_t)NN * NN;

    const unsigned short* A;
    const unsigned short* B;
    if constexpr (MODE == 2) { A = Abase + (size_t)z * bnc; B = Bbase + (size_t)z * bnc; }
    else                     { A = Abase + (size_t)z * bss; B = Bbase + (size_t)z * bnc; }

    // supertile swizzle
    constexpr int TPS = SW * SH;
    constexpr int SPR = TX / SW;          // supertiles per row
    const int st = blockIdx.x / TPS;
    const int wi = blockIdx.x % TPS;
    const int bx = (st % SPR) * SW + wi % SW;
    const int by = (st / SPR) * SH + wi / SW;
    const int m0 = by * BM;
    const int n0 = bx * BN;

    __shared__ __attribute__((aligned(16))) unsigned short As[BM * 32];
    __shared__ __attribute__((aligned(16))) unsigned short Bs[BN * 32];

    const int t = threadIdx.x;
    const int lane = t & 63;
    const int w = t >> 6;
    const int wr = w >> 1, wc = w & 1;

    const int sr = w * 16 + (lane >> 2);
    const int sc8 = (lane & 3) * 8;
    const int lds_elem = w * 512;

    floatx4 acc[FI][FJ] = {};

    for (int k0 = 0; k0 < K; k0 += 32) {
#pragma unroll
        for (int s = 0; s < BM / 64; ++s)
            gload_lds16(A + (size_t)(m0 + s * 64 + sr) * K + k0 + sc8,
                        As + s * 2048 + lds_elem);
#pragma unroll
        for (int s = 0; s < BN / 64; ++s)
            gload_lds16(B + (size_t)(n0 + s * 64 + sr) * K + k0 + sc8,
                        Bs + s * 2048 + lds_elem);
        __syncthreads();

        bf16x8 af[FI], bfr[FJ];
        const unsigned short* Ab = As + ((wr * (BM / 2) + (lane & 15)) * 32) + (lane >> 4) * 8;
        const unsigned short* Bb = Bs + ((wc * (BN / 2) + (lane & 15)) * 32) + (lane >> 4) * 8;
#pragma unroll
        for (int i = 0; i < FI; ++i) af[i]  = *(const bf16x8*)(Ab + i * 16 * 32);
#pragma unroll
        for (int j = 0; j < FJ; ++j) bfr[j] = *(const bf16x8*)(Bb + j * 16 * 32);
#pragma unroll
        for (int i = 0; i < FI; ++i)
#pragma unroll
            for (int j = 0; j < FJ; ++j)
                acc[i][j] = __builtin_amdgcn_mfma_f32_16x16x32_bf16(
                    af[i], bfr[j], acc[i][j], 0, 0, 0);
        __syncthreads();
    }

    const int fr = lane >> 4;
    const int fc = lane & 15;

    if constexpr (MODE == 2) {
        float rs[FI][4];
#pragma unroll
        for (int i = 0; i < FI; ++i)
#pragma unroll
            for (int r = 0; r < 4; ++r) rs[i][r] = 0.f;
#pragma unroll
        for (int i = 0; i < FI; ++i) {
#pragma unroll
            for (int j = 0; j < FJ; ++j) {
                int n = n0 + wc * (BN / 2) + j * 16 + fc;
                int mbase = m0 + wr * (BM / 2) + i * 16 + fr * 4;
#pragma unroll
                for (int r = 0; r < 4; ++r) {
                    float e = __expf(acc[i][j][r]);
                    ob0[(size_t)z * bss + (size_t)(mbase + r) * NN + n] = f2bf_trunc(e);
                    rs[i][r] += e;
                }
            }
        }
#pragma unroll
        for (int i = 0; i < FI; ++i) {
#pragma unroll
            for (int r = 0; r < 4; ++r) {
                float v = rs[i][r];
                v += __shfl_xor(v, 1, 16);
                v += __shfl_xor(v, 2, 16);
                v += __shfl_xor(v, 4, 16);
                v += __shfl_xor(v, 8, 16);
                if (fc == 0) {
                    int m = m0 + wr * (BM / 2) + i * 16 + fr * 4 + r;
                    atomicAdd(&L[z * NN + m], v);
                }
            }
        }
    } else {   // MODE 3
#pragma unroll
        for (int i = 0; i < FI; ++i) {
#pragma unroll
            for (int r = 0; r < 4; ++r) {
                int m = m0 + wr * (BM / 2) + i * 16 + fr * 4 + r;
                float linv = 1.0f / L[z * NN + m];
#pragma unroll
                for (int j = 0; j < FJ; ++j) {
                    int n = n0 + wc * (BN / 2) + j * 16 + fc;
                    ob0[(size_t)z * bnc + (size_t)m * NC + n] = f2bf(acc[i][j][r] * linv);
                }
            }
        }
    }
}

// ---------------------------------------------------------------------------
extern "C" void kernel_launch(void* const* d_in, const int* in_sizes, int n_in,
                              void* d_out, int out_size, void* d_ws, size_t ws_size,
                              hipStream_t stream)
{
    const float* x     = (const float*)d_in[0];
    const float* gn_w  = (const float*)d_in[1];
    const float* gn_b  = (const float*)d_in[2];
    const float* qkv_w = (const float*)d_in[3];
    const float* qkv_b = (const float*)d_in[4];
    const float* out_w = (const float*)d_in[5];
    const float* out_b = (const float*)d_in[6];
    float* out = (float*)d_out;

    const size_t bnc = (size_t)NN * NC;          // 2,097,152 per batch
    char* w = (char*)d_ws;
    float* ss   = (float*)w;                 w += 16384;
    float* part = (float*)w;                 w += 8192;
    float* Lsum = (float*)w;                 w += (size_t)NB * NN * 4;  // row sums
    unsigned short* wq = (unsigned short*)w; w += (size_t)1536 * 512 * 2;
    unsigned short* wo = (unsigned short*)w; w += (size_t)512 * 512 * 2;
    unsigned short* qt = (unsigned short*)w; w += NB * bnc * 2;   // (b,n,c) pre-scaled
    unsigned short* kt = (unsigned short*)w; w += NB * bnc * 2;   // (b,n,c)
    unsigned short* vt = (unsigned short*)w; w += NB * bnc * 2;   // (b,c,n)
    unsigned short* SP = (unsigned short*)w; w += (size_t)NB * NN * NN * 2; // 128 MB
    // Aliases (lifetime-disjoint):
    unsigned short* ht = SP;   // ht (b,n,c) dead before MODE 2 writes SP
    unsigned short* Ob = qt;   // Ob (b,n,c) written after qt last read (MODE 2)

    hipMemsetAsync(Lsum, 0, (size_t)NB * NN * sizeof(float), stream);

    gn_partial_kernel<<<1024, 256, 0, stream>>>(x, part);
    gn_final_kernel<<<1, 128, 0, stream>>>(part, gn_w, gn_b, ss);
    wconv_kernel<<<(1536 * 512 + 512 * 512) / 256, 256, 0, stream>>>(qkv_w, out_w, wq, wo);
    htnorm_kernel<<<dim3(NN / 32, NC / 32, NB), 256, 0, stream>>>(x, ss, ht);

    // q/k: C[p,o] = ht · wqk^T   (q pre-scaled by ATTN_SCALE)
    mfma_gemm<0, 128, 128><<<dim3(1024 / 128, NN / 128, NB), 256, 0, stream>>>(
        ht, wq, qkv_b, nullptr, nullptr, qt, kt);
    // v: C[c,p] = wv · ht^T
    mfma_gemm<1, 128, 128><<<dim3(NN / 128, 512 / 128, NB), 256, 0, stream>>>(
        wq + (size_t)1024 * 512, ht, qkv_b, nullptr, nullptr, vt, nullptr);

    // QK^T + exp + row-sum, swizzled (32x32 tiles, 8x4 supertiles)
    attn_gemm<2, 128, 128, 32, 8, 4><<<dim3(1024, 1, NB), 256, 0, stream>>>(
        qt, kt, Lsum, SP);
    // PV + normalize, swizzled (4x64 tiles of 64x128, 4x8 supertiles) -> 4 blk/CU
    attn_gemm<3, 64, 128, 4, 4, 8><<<dim3(256, 1, NB), 256, 0, stream>>>(
        SP, vt, Lsum, Ob);

    // out projection + bias + residual
    mfma_gemm<4, 128, 128><<<dim3(NN / 128, 512 / 128, NB), 256, 0, stream>>>(
        wo, Ob, out_b, x, out, nullptr, nullptr);
}